// Round 18
// baseline (103.030 us; speedup 1.0000x reference)
//
#include <hip/hip_runtime.h>
#include <hip/hip_bf16.h>

#define NPTS 256
#define DDIM 256
#define MT 16          // main-kernel m-tile
#define MTILE 32       // fallback m-tile
#define BLOCK 512

typedef __attribute__((ext_vector_type(4))) float f32x4;
typedef __attribute__((ext_vector_type(8))) short s16x8;

static __device__ __forceinline__ short f2bf(float f) {
  unsigned int u = __builtin_bit_cast(unsigned int, f);
  u += 0x7fffu + ((u >> 16) & 1u);   // round-to-nearest-even
  return (short)(unsigned short)(u >> 16);
}

static __device__ __forceinline__ unsigned long long shfl_xor_u64(unsigned long long v, int off) {
  unsigned int hi = (unsigned int)(v >> 32);
  unsigned int lo = (unsigned int)v;
  hi = (unsigned int)__shfl_xor((int)hi, off);
  lo = (unsigned int)__shfl_xor((int)lo, off);
  return ((unsigned long long)hi << 32) | (unsigned long long)lo;
}

// ---- fused prep: blocks 0..63 pack W; blocks 64.. wave-parallel kNN (R16-validated) ----
__global__ __launch_bounds__(256) void prep(const float* __restrict__ pts,
                                            const float* __restrict__ Wd,
                                            const float* __restrict__ Wa,
                                            s16x8* __restrict__ PW,
                                            int* __restrict__ knn_out, int total) {
#pragma clang fp contract(off)
  const int tid = threadIdx.x;
  if (blockIdx.x < 64) {
    const int flat = blockIdx.x * 256 + tid;     // 0..16383
    const int l = flat & 63;
    const int cf = (flat >> 6) & 1;
    const int ks = (flat >> 7) & 7;
    const int wid = (flat >> 10) & 7;
    const int mat = (flat >> 13) & 1;
    const float* W = mat ? Wa : Wd;
    const int dl = wid * 32 + cf * 16 + (l & 15);
    const int kb = ks * 32 + (l >> 4) * 8;
    const float* src = W + dl * DDIM + kb;
    const f32x4 f0 = *reinterpret_cast<const f32x4*>(src);
    const f32x4 f1 = *reinterpret_cast<const f32x4*>(src + 4);
    s16x8 v;
#pragma unroll
    for (int e = 0; e < 4; ++e) { v[e] = f2bf(f0[e]); v[e + 4] = f2bf(f1[e]); }
    PW[flat] = v;
    return;
  }
  const int task = (blockIdx.x - 64) * 4 + (tid >> 6);
  if (task >= total) return;
  const int lane = tid & 63;
  const int b = task >> 8, n = task & 255;
  const float* P = pts + b * 768;
  const float px = P[3 * n], py = P[3 * n + 1], pz = P[3 * n + 2];
  const float sqn = (px * px + py * py) + pz * pz;

  unsigned long long key[4];
#pragma unroll
  for (int q = 0; q < 4; ++q) {
    const int m = lane + 64 * q;
    const float x = P[3 * m], y = P[3 * m + 1], z = P[3 * m + 2];
    const float sqm = (x * x + y * y) + z * z;
    const float dt = (px * x + py * y) + pz * z;
    const float d2 = (sqn + sqm) - 2.0f * dt;
    const float dist = sqrtf(fmaxf(d2, 0.0f));
    key[q] = ((unsigned long long)__builtin_bit_cast(unsigned int, dist) << 32) |
             (unsigned long long)(unsigned int)m;
  }
  int kn[4];
#pragma unroll
  for (int r = 0; r < 4; ++r) {
    unsigned long long kmin = key[0];
#pragma unroll
    for (int q = 1; q < 4; ++q) kmin = (key[q] < kmin) ? key[q] : kmin;
#pragma unroll
    for (int off = 32; off > 0; off >>= 1) {
      unsigned long long o = shfl_xor_u64(kmin, off);
      kmin = (o < kmin) ? o : kmin;
    }
    kn[r] = (int)(unsigned int)(kmin & 0xffffffffULL);
#pragma unroll
    for (int q = 0; q < 4; ++q)
      if (key[q] == kmin) key[q] = ~0ULL;
  }
  if (lane == 0) {
    knn_out[task * 3 + 0] = kn[1];
    knn_out[task * 3 + 1] = kn[2];
    knn_out[task * 3 + 2] = kn[3];
  }
}

// -------- main kernel: MT=16 tile, 32KB LDS; bounds (512,4) — single change vs R17 --------
__global__ __launch_bounds__(BLOCK, 4) void rpe_main(
    const float* __restrict__ pts, const int* __restrict__ knn,
    const s16x8* __restrict__ PW,
    const float* __restrict__ bdv, const float* __restrict__ bav,
    float* __restrict__ out) {
#pragma clang fp contract(off)
  __shared__ alignas(16) unsigned char Elds[4 * MT * DDIM * 2];   // 32 KB

  const int b = blockIdx.z;
  const int n = blockIdx.y;
  const int mbase = blockIdx.x * MT;
  const int tid = threadIdx.x;
  const int lane = tid & 63;

  const float* Pb = pts + b * NPTS * 3;
  const float pnx = Pb[n * 3 + 0], pny = Pb[n * 3 + 1], pnz = Pb[n * 3 + 2];
  const float sqn = (pnx * pnx + pny * pny) + pnz * pnz;

  const int kb3 = (b * NPTS + n) * 3;
  const int kn1 = knn[kb3 + 0], kn2 = knn[kb3 + 1], kn3 = knn[kb3 + 2];
  const float r0x = Pb[kn1 * 3 + 0] - pnx, r0y = Pb[kn1 * 3 + 1] - pny, r0z = Pb[kn1 * 3 + 2] - pnz;
  const float r1x = Pb[kn2 * 3 + 0] - pnx, r1y = Pb[kn2 * 3 + 1] - pny, r1z = Pb[kn2 * 3 + 2] - pnz;
  const float r2x = Pb[kn3 * 3 + 0] - pnx, r2y = Pb[kn3 * 3 + 1] - pny, r2z = Pb[kn3 * 3 + 2] - pnz;

  // ---- E-tile generation (row-major, XOR-swizzled; 16 sincos/thread) ----
  {
    const int p = tid >> 7;            // 0..3
    const int r128 = tid & 127;
    const int ml = r128 & 15;          // row 0..15
    const int kc = r128 >> 4;          // 0..7
    const int k0 = kc << 5;            // elem 0,32,...,224
    const int m = mbase + ml;
    const float pmx = Pb[m * 3 + 0], pmy = Pb[m * 3 + 1], pmz = Pb[m * 3 + 2];
    float xv;
    if (p == 0) {
      const float sqm = (pmx * pmx + pmy * pmy) + pmz * pmz;
      const float dt = (pnx * pmx + pny * pmy) + pnz * pmz;
      const float d2 = (sqn + sqm) - 2.0f * dt;
      xv = sqrtf(fmaxf(d2, 0.0f)) / 0.2f;
    } else {
      const float ax = pmx - pnx, ay = pmy - pny, az = pmz - pnz;
      const float rx = (p == 1) ? r0x : (p == 2) ? r1x : r2x;
      const float ry = (p == 1) ? r0y : (p == 2) ? r1y : r2y;
      const float rz = (p == 1) ? r0z : (p == 2) ? r1z : r2z;
      const float cx = ry * az - rz * ay;
      const float cy = rz * ax - rx * az;
      const float cz = rx * ay - ry * ax;
      const float sv = sqrtf((cx * cx + cy * cy) + cz * cz);
      const float cv = (rx * ax + ry * ay) + rz * az;
      // XLA +0 reduction-identity: a==0 -> cos=+0 -> angle 0 (never pi)
      float ang;
      if (sv == 0.0f && cv == 0.0f) ang = 0.0f;
      else ang = atan2f(sv, cv);
      xv = ang * 3.8197186342054885f;
    }
    const int row = (p << 4) + ml;
    const int swz = (ml & 7) << 4;
    const float c_exp = -0.10381025296523007f;     // -log2(10000)/128
    float w = exp2f((float)(kc << 4) * c_exp);
    const float step = 0.93057204f;                // 10000^(-1/128)
#pragma unroll
    for (int c = 0; c < 4; ++c) {
      int4 v;
#pragma unroll
      for (int jj = 0; jj < 4; ++jj) {
        const float om = xv * w;
        float s, cc;
        __sincosf(om, &s, &cc);
        unsigned int pk;
        asm("v_cvt_pk_bf16_f32 %0, %1, %2" : "=v"(pk) : "v"(s), "v"(cc));
        ((unsigned int*)&v)[jj] = pk;
        w *= step;
      }
      const int boff = ((k0 << 1) + (c << 4)) ^ swz;
      *reinterpret_cast<int4*>(&Elds[row * 512 + boff]) = v;
    }
  }
  __syncthreads();

  // ---- fused 4-path GEMM: per wave 16 rows x 32 cols ----
  const int wid = tid >> 6;
  const int lrow = lane & 15;

  f32x4 acc[4][2];
  const f32x4 zero = {0.0f, 0.0f, 0.0f, 0.0f};
#pragma unroll
  for (int p = 0; p < 4; ++p) {
    acc[p][0] = zero; acc[p][1] = zero;
  }

#pragma unroll
  for (int ks = 0; ks < 8; ++ks) {
    const int ib = ((wid * 8 + ks) * 2) * 64 + lane;
    const s16x8 wd0 = PW[ib];
    const s16x8 wd1 = PW[ib + 64];
    const s16x8 wa0 = PW[ib + 8192];
    const s16x8 wa1 = PW[ib + 8192 + 64];

    const int kbyte = ((ks << 5) + ((lane >> 4) << 3)) << 1;
    const int boff = kbyte ^ ((lrow & 7) << 4);
#pragma unroll
    for (int p = 0; p < 4; ++p) {
      const s16x8 af =
          *reinterpret_cast<const s16x8*>(&Elds[((p << 4) + lrow) * 512 + boff]);
      acc[p][0] = __builtin_amdgcn_mfma_f32_16x16x32_bf16(
          af, p == 0 ? wd0 : wa0, acc[p][0], 0, 0, 0);
      acc[p][1] = __builtin_amdgcn_mfma_f32_16x16x32_bf16(
          af, p == 0 ? wd1 : wa1, acc[p][1], 0, 0, 0);
    }
  }

  // ---- epilogue ----
  const long nbase = (long)(b * NPTS + n) * NPTS + mbase;
  const int dbase = wid << 5;
#pragma unroll
  for (int cf = 0; cf < 2; ++cf) {
    const int dl = dbase + (cf << 4) + lrow;
    const float bias = bdv[dl] + bav[dl];
    const f32x4 vd = acc[0][cf];
    const f32x4 a0 = acc[1][cf];
    const f32x4 a1 = acc[2][cf];
    const f32x4 a2 = acc[3][cf];
#pragma unroll
    for (int g = 0; g < 4; ++g) {
      const int mrow = ((lane >> 4) << 2) + g;   // 0..15
      const float val = vd[g] + fmaxf(fmaxf(a0[g], a1[g]), a2[g]) + bias;
      out[(nbase + mrow) * DDIM + dl] = val;
    }
  }
}

// ---------------- fallback: validated R13 all-in-one kernel (MTILE=32) ----------------
__global__ __launch_bounds__(BLOCK, 1) void rpe_fused(
    const float* __restrict__ pts,
    const float* __restrict__ Wd, const float* __restrict__ bd,
    const float* __restrict__ Wa, const float* __restrict__ ba,
    float* __restrict__ out) {
#pragma clang fp contract(off)
  __shared__ alignas(16) unsigned char Elds[4 * MTILE * DDIM * 2];

  const int b = blockIdx.z;
  const int n = blockIdx.y;
  const int mbase = blockIdx.x * MTILE;
  const int tid = threadIdx.x;
  const int lane = tid & 63;

  const float* Pb = pts + b * NPTS * 3;
  const float pnx = Pb[n * 3 + 0], pny = Pb[n * 3 + 1], pnz = Pb[n * 3 + 2];
  const float sqn = (pnx * pnx + pny * pny) + pnz * pnz;

  unsigned long long key[4];
#pragma unroll
  for (int q = 0; q < 4; ++q) {
    const int m = lane + 64 * q;
    const float x = Pb[m * 3 + 0], y = Pb[m * 3 + 1], z = Pb[m * 3 + 2];
    const float sqm = (x * x + y * y) + z * z;
    const float dt = (pnx * x + pny * y) + pnz * z;
    const float d2 = (sqn + sqm) - 2.0f * dt;
    const float dist = sqrtf(fmaxf(d2, 0.0f));
    key[q] = ((unsigned long long)__builtin_bit_cast(unsigned int, dist) << 32) |
             (unsigned long long)(unsigned int)m;
  }
  int knn1 = 0, knn2 = 0, knn3 = 0;
#pragma unroll
  for (int r = 0; r < 4; ++r) {
    unsigned long long kmin = key[0];
#pragma unroll
    for (int q = 1; q < 4; ++q) kmin = (key[q] < kmin) ? key[q] : kmin;
#pragma unroll
    for (int off = 32; off > 0; off >>= 1) {
      unsigned long long o = shfl_xor_u64(kmin, off);
      kmin = (o < kmin) ? o : kmin;
    }
    const int widx = (int)(unsigned int)(kmin & 0xffffffffULL);
    if (r == 1) knn1 = widx;
    if (r == 2) knn2 = widx;
    if (r == 3) knn3 = widx;
#pragma unroll
    for (int q = 0; q < 4; ++q)
      if (key[q] == kmin) key[q] = ~0ULL;
  }
  const float r0x = Pb[knn1 * 3 + 0] - pnx, r0y = Pb[knn1 * 3 + 1] - pny, r0z = Pb[knn1 * 3 + 2] - pnz;
  const float r1x = Pb[knn2 * 3 + 0] - pnx, r1y = Pb[knn2 * 3 + 1] - pny, r1z = Pb[knn2 * 3 + 2] - pnz;
  const float r2x = Pb[knn3 * 3 + 0] - pnx, r2y = Pb[knn3 * 3 + 1] - pny, r2z = Pb[knn3 * 3 + 2] - pnz;

  {
    const int p = tid >> 7;
    const int r128 = tid & 127;
    const int ml = r128 & 31;
    const int k0 = (r128 >> 5) << 6;
    const int m = mbase + ml;
    const float pmx = Pb[m * 3 + 0], pmy = Pb[m * 3 + 1], pmz = Pb[m * 3 + 2];
    float xv;
    if (p == 0) {
      const float sqm = (pmx * pmx + pmy * pmy) + pmz * pmz;
      const float dt = (pnx * pmx + pny * pmy) + pnz * pmz;
      const float d2 = (sqn + sqm) - 2.0f * dt;
      xv = sqrtf(fmaxf(d2, 0.0f)) / 0.2f;
    } else {
      const float ax = pmx - pnx, ay = pmy - pny, az = pmz - pnz;
      const float rx = (p == 1) ? r0x : (p == 2) ? r1x : r2x;
      const float ry = (p == 1) ? r0y : (p == 2) ? r1y : r2y;
      const float rz = (p == 1) ? r0z : (p == 2) ? r1z : r2z;
      const float cx = ry * az - rz * ay;
      const float cy = rz * ax - rx * az;
      const float cz = rx * ay - ry * ax;
      const float sv = sqrtf((cx * cx + cy * cy) + cz * cz);
      const float cv = (rx * ax + ry * ay) + rz * az;
      float ang;
      if (sv == 0.0f && cv == 0.0f) ang = 0.0f;
      else ang = atan2f(sv, cv);
      xv = ang * 3.8197186342054885f;
    }
    const int row = (p << 5) + ml;
    const int swz = (ml & 7) << 4;
    const float c_exp = -0.10381025296523007f;
    const int jbase = k0 >> 1;
#pragma unroll
    for (int c = 0; c < 8; ++c) {
      s16x8 v;
#pragma unroll
      for (int jj = 0; jj < 4; ++jj) {
        const int j = jbase + c * 4 + jj;
        const float w = exp2f((float)j * c_exp);
        const float om = xv * w;
        float s, cc;
        __sincosf(om, &s, &cc);
        v[2 * jj] = f2bf(s);
        v[2 * jj + 1] = f2bf(cc);
      }
      const int boff = ((k0 << 1) + (c << 4)) ^ swz;
      *reinterpret_cast<s16x8*>(&Elds[row * 512 + boff]) = v;
    }
  }
  __syncthreads();

  const int wid = tid >> 6;
  const int dbase = wid << 5;
  const int lrow = lane & 15;
  const int lkb = (lane >> 4) << 3;

  f32x4 acc[4][2][2];
  const f32x4 zero = {0.0f, 0.0f, 0.0f, 0.0f};
#pragma unroll
  for (int p = 0; p < 4; ++p)
#pragma unroll
    for (int rf = 0; rf < 2; ++rf)
#pragma unroll
      for (int cf = 0; cf < 2; ++cf) acc[p][rf][cf] = zero;

#pragma unroll
  for (int ks = 0; ks < 8; ++ks) {
    const int kb = (ks << 5) + lkb;
    s16x8 bw[2][2];
#pragma unroll
    for (int cf = 0; cf < 2; ++cf) {
      const int dl = dbase + (cf << 4) + lrow;
      const float* wpd = Wd + dl * DDIM + kb;
      const float* wpa = Wa + dl * DDIM + kb;
      const f32x4 f0 = *reinterpret_cast<const f32x4*>(wpd);
      const f32x4 f1 = *reinterpret_cast<const f32x4*>(wpd + 4);
      const f32x4 g0 = *reinterpret_cast<const f32x4*>(wpa);
      const f32x4 g1 = *reinterpret_cast<const f32x4*>(wpa + 4);
      s16x8 vd, va;
#pragma unroll
      for (int e = 0; e < 4; ++e) {
        vd[e] = f2bf(f0[e]); vd[e + 4] = f2bf(f1[e]);
        va[e] = f2bf(g0[e]); va[e + 4] = f2bf(g1[e]);
      }
      bw[0][cf] = vd; bw[1][cf] = va;
    }
    const int kbyte = kb << 1;
#pragma unroll
    for (int rf = 0; rf < 2; ++rf) {
      const int mrow = (rf << 4) + lrow;
      const int boff = kbyte ^ ((mrow & 7) << 4);
#pragma unroll
      for (int p = 0; p < 4; ++p) {
        const s16x8 af =
            *reinterpret_cast<const s16x8*>(&Elds[((p << 5) + mrow) * 512 + boff]);
        acc[p][rf][0] = __builtin_amdgcn_mfma_f32_16x16x32_bf16(
            af, bw[p == 0 ? 0 : 1][0], acc[p][rf][0], 0, 0, 0);
        acc[p][rf][1] = __builtin_amdgcn_mfma_f32_16x16x32_bf16(
            af, bw[p == 0 ? 0 : 1][1], acc[p][rf][1], 0, 0, 0);
      }
    }
  }

  const long nbase = (long)(b * NPTS + n) * NPTS + mbase;
#pragma unroll
  for (int cf = 0; cf < 2; ++cf) {
    const int dl = dbase + (cf << 4) + lrow;
    const float bias = bd[dl] + ba[dl];
#pragma unroll
    for (int rf = 0; rf < 2; ++rf) {
      const f32x4 vd = acc[0][rf][cf];
      const f32x4 a0 = acc[1][rf][cf];
      const f32x4 a1 = acc[2][rf][cf];
      const f32x4 a2 = acc[3][rf][cf];
#pragma unroll
      for (int g = 0; g < 4; ++g) {
        const int mrow = (rf << 4) + ((lane >> 4) << 2) + g;
        const float val = vd[g] + fmaxf(fmaxf(a0[g], a1[g]), a2[g]) + bias;
        out[(nbase + mrow) * DDIM + dl] = val;
      }
    }
  }
}

extern "C" void kernel_launch(void* const* d_in, const int* in_sizes, int n_in,
                              void* d_out, int out_size, void* d_ws, size_t ws_size,
                              hipStream_t stream) {
  const float* pts = (const float*)d_in[0];
  const float* Wd  = (const float*)d_in[1];
  const float* bd  = (const float*)d_in[2];
  const float* Wa  = (const float*)d_in[3];
  const float* ba  = (const float*)d_in[4];
  float* out = (float*)d_out;
  const int B = in_sizes[0] / (NPTS * 3);
  const int total = B * NPTS;

  const size_t PW_BYTES = 16384 * 16;                 // 256 KB packed W
  const size_t need = PW_BYTES + (size_t)total * 3 * 4;

  if (ws_size >= need) {
    s16x8* PW = (s16x8*)d_ws;
    int* knn = (int*)((char*)d_ws + PW_BYTES);
    const int knn_blocks = (total + 3) / 4;
    prep<<<64 + knn_blocks, 256, 0, stream>>>(pts, Wd, Wa, PW, knn, total);
    dim3 grid(NPTS / MT, NPTS, B);
    rpe_main<<<grid, BLOCK, 0, stream>>>(pts, knn, PW, bd, ba, out);
  } else {
    dim3 grid(NPTS / MTILE, NPTS, B);
    rpe_fused<<<grid, BLOCK, 0, stream>>>(pts, Wd, bd, Wa, ba, out);
  }
}

// Round 20
// 82.399 us; speedup vs baseline: 1.2504x; 1.2504x over previous
//
#include <hip/hip_runtime.h>
#include <hip/hip_bf16.h>

#define NPTS 256
#define DDIM 256
#define MTILE 32
#define BLOCK 512

typedef __attribute__((ext_vector_type(4))) float f32x4;
typedef __attribute__((ext_vector_type(8))) short s16x8;

static __device__ __forceinline__ short f2bf(float f) {
  unsigned int u = __builtin_bit_cast(unsigned int, f);
  u += 0x7fffu + ((u >> 16) & 1u);   // round-to-nearest-even
  return (short)(unsigned short)(u >> 16);
}

static __device__ __forceinline__ unsigned long long shfl_xor_u64(unsigned long long v, int off) {
  unsigned int hi = (unsigned int)(v >> 32);
  unsigned int lo = (unsigned int)v;
  hi = (unsigned int)__shfl_xor((int)hi, off);
  lo = (unsigned int)__shfl_xor((int)lo, off);
  return ((unsigned long long)hi << 32) | (unsigned long long)lo;
}

// ---- fused prep: blocks 0..63 pack W; blocks 64.. wave-parallel kNN (R16-validated) ----
__global__ __launch_bounds__(256) void prep(const float* __restrict__ pts,
                                            const float* __restrict__ Wd,
                                            const float* __restrict__ Wa,
                                            s16x8* __restrict__ PW,
                                            int* __restrict__ knn_out, int total) {
#pragma clang fp contract(off)
  const int tid = threadIdx.x;
  if (blockIdx.x < 64) {
    const int flat = blockIdx.x * 256 + tid;     // 0..16383
    const int l = flat & 63;
    const int cf = (flat >> 6) & 1;
    const int ks = (flat >> 7) & 7;
    const int wid = (flat >> 10) & 7;
    const int mat = (flat >> 13) & 1;
    const float* W = mat ? Wa : Wd;
    const int dl = wid * 32 + cf * 16 + (l & 15);
    const int kb = ks * 32 + (l >> 4) * 8;
    const float* src = W + dl * DDIM + kb;
    const f32x4 f0 = *reinterpret_cast<const f32x4*>(src);
    const f32x4 f1 = *reinterpret_cast<const f32x4*>(src + 4);
    s16x8 v;
#pragma unroll
    for (int e = 0; e < 4; ++e) { v[e] = f2bf(f0[e]); v[e + 4] = f2bf(f1[e]); }
    PW[flat] = v;
    return;
  }
  const int task = (blockIdx.x - 64) * 4 + (tid >> 6);
  if (task >= total) return;
  const int lane = tid & 63;
  const int b = task >> 8, n = task & 255;
  const float* P = pts + b * 768;
  const float px = P[3 * n], py = P[3 * n + 1], pz = P[3 * n + 2];
  const float sqn = (px * px + py * py) + pz * pz;

  unsigned long long key[4];
#pragma unroll
  for (int q = 0; q < 4; ++q) {
    const int m = lane + 64 * q;
    const float x = P[3 * m], y = P[3 * m + 1], z = P[3 * m + 2];
    const float sqm = (x * x + y * y) + z * z;
    const float dt = (px * x + py * y) + pz * z;
    const float d2 = (sqn + sqm) - 2.0f * dt;
    const float dist = sqrtf(fmaxf(d2, 0.0f));
    key[q] = ((unsigned long long)__builtin_bit_cast(unsigned int, dist) << 32) |
             (unsigned long long)(unsigned int)m;
  }
  int kn[4];
#pragma unroll
  for (int r = 0; r < 4; ++r) {
    unsigned long long kmin = key[0];
#pragma unroll
    for (int q = 1; q < 4; ++q) kmin = (key[q] < kmin) ? key[q] : kmin;
#pragma unroll
    for (int off = 32; off > 0; off >>= 1) {
      unsigned long long o = shfl_xor_u64(kmin, off);
      kmin = (o < kmin) ? o : kmin;
    }
    kn[r] = (int)(unsigned int)(kmin & 0xffffffffULL);
#pragma unroll
    for (int q = 0; q < 4; ++q)
      if (key[q] == kmin) key[q] = ~0ULL;
  }
  if (lane == 0) {
    knn_out[task * 3 + 0] = kn[1];
    knn_out[task * 3 + 1] = kn[2];
    knn_out[task * 3 + 2] = kn[3];
  }
}

// ---- main kernel: byte-exact R16 structure + s_setprio around GEMM (single change) ----
__global__ __launch_bounds__(BLOCK, 4) void rpe_main(
    const float* __restrict__ pts, const int* __restrict__ knn,
    const s16x8* __restrict__ PW,
    const float* __restrict__ bdv, const float* __restrict__ bav,
    float* __restrict__ out) {
#pragma clang fp contract(off)
  __shared__ alignas(16) unsigned char Elds[4 * MTILE * DDIM * 2];   // 64 KB

  const int b = blockIdx.z;
  const int n = blockIdx.y;
  const int mbase = blockIdx.x * MTILE;
  const int tid = threadIdx.x;
  const int lane = tid & 63;

  const float* Pb = pts + b * NPTS * 3;
  const float pnx = Pb[n * 3 + 0], pny = Pb[n * 3 + 1], pnz = Pb[n * 3 + 2];
  const float sqn = (pnx * pnx + pny * pny) + pnz * pnz;

  const int kb3 = (b * NPTS + n) * 3;
  const int kn1 = knn[kb3 + 0], kn2 = knn[kb3 + 1], kn3 = knn[kb3 + 2];
  const float r0x = Pb[kn1 * 3 + 0] - pnx, r0y = Pb[kn1 * 3 + 1] - pny, r0z = Pb[kn1 * 3 + 2] - pnz;
  const float r1x = Pb[kn2 * 3 + 0] - pnx, r1y = Pb[kn2 * 3 + 1] - pny, r1z = Pb[kn2 * 3 + 2] - pnz;
  const float r2x = Pb[kn3 * 3 + 0] - pnx, r2y = Pb[kn3 * 3 + 1] - pny, r2z = Pb[kn3 * 3 + 2] - pnz;

  // ---- E-tile generation (row-major, XOR-swizzled) ----
  {
    const int p = tid >> 7;           // 0..3
    const int r128 = tid & 127;
    const int ml = r128 & 31;
    const int k0 = (r128 >> 5) << 6;  // 0,64,128,192
    const int m = mbase + ml;
    const float pmx = Pb[m * 3 + 0], pmy = Pb[m * 3 + 1], pmz = Pb[m * 3 + 2];
    float xv;
    if (p == 0) {
      const float sqm = (pmx * pmx + pmy * pmy) + pmz * pmz;
      const float dt = (pnx * pmx + pny * pmy) + pnz * pmz;
      const float d2 = (sqn + sqm) - 2.0f * dt;
      xv = sqrtf(fmaxf(d2, 0.0f)) / 0.2f;
    } else {
      const float ax = pmx - pnx, ay = pmy - pny, az = pmz - pnz;
      const float rx = (p == 1) ? r0x : (p == 2) ? r1x : r2x;
      const float ry = (p == 1) ? r0y : (p == 2) ? r1y : r2y;
      const float rz = (p == 1) ? r0z : (p == 2) ? r1z : r2z;
      const float cx = ry * az - rz * ay;
      const float cy = rz * ax - rx * az;
      const float cz = rx * ay - ry * ax;
      const float sv = sqrtf((cx * cx + cy * cy) + cz * cz);
      const float cv = (rx * ax + ry * ay) + rz * az;
      // XLA +0 reduction-identity: a==0 -> cos=+0 -> angle 0 (never pi)
      float ang;
      if (sv == 0.0f && cv == 0.0f) ang = 0.0f;
      else ang = atan2f(sv, cv);
      xv = ang * 3.8197186342054885f;
    }
    const int row = (p << 5) + ml;
    const int swz = (ml & 7) << 4;
    const float c_exp = -0.10381025296523007f;     // -log2(10000)/128
    const int jbase = k0 >> 1;
    float w = exp2f((float)jbase * c_exp);
    const float step = 0.93057204f;                // 10000^(-1/128)
#pragma unroll
    for (int c = 0; c < 8; ++c) {
      int4 v;
#pragma unroll
      for (int jj = 0; jj < 4; ++jj) {
        const float om = xv * w;
        float s, cc;
        __sincosf(om, &s, &cc);
        unsigned int pk;
        asm("v_cvt_pk_bf16_f32 %0, %1, %2" : "=v"(pk) : "v"(s), "v"(cc));
        ((unsigned int*)&v)[jj] = pk;
        w *= step;
      }
      const int boff = ((k0 << 1) + (c << 4)) ^ swz;
      *reinterpret_cast<int4*>(&Elds[row * 512 + boff]) = v;
    }
  }
  __syncthreads();

  // ---- fused 4-path GEMM (setprio hints MFMA-phase waves over E-gen waves) ----
  const int wid = tid >> 6;
  const int lrow = lane & 15;

  f32x4 acc[4][2][2];
  const f32x4 zero = {0.0f, 0.0f, 0.0f, 0.0f};
#pragma unroll
  for (int p = 0; p < 4; ++p)
#pragma unroll
    for (int rf = 0; rf < 2; ++rf)
#pragma unroll
      for (int cf = 0; cf < 2; ++cf) acc[p][rf][cf] = zero;

  __builtin_amdgcn_s_setprio(1);
#pragma unroll
  for (int ks = 0; ks < 8; ++ks) {
    const int ib = ((wid * 8 + ks) * 2) * 64 + lane;
    const s16x8 wd0 = PW[ib];
    const s16x8 wd1 = PW[ib + 64];
    const s16x8 wa0 = PW[ib + 8192];
    const s16x8 wa1 = PW[ib + 8192 + 64];

    const int kb = (ks << 5) + ((lane >> 4) << 3);
    const int kbyte = kb << 1;
#pragma unroll
    for (int rf = 0; rf < 2; ++rf) {
      const int mrow = (rf << 4) + lrow;
      const int boff = kbyte ^ ((mrow & 7) << 4);
#pragma unroll
      for (int p = 0; p < 4; ++p) {
        const s16x8 af =
            *reinterpret_cast<const s16x8*>(&Elds[((p << 5) + mrow) * 512 + boff]);
        acc[p][rf][0] = __builtin_amdgcn_mfma_f32_16x16x32_bf16(
            af, p == 0 ? wd0 : wa0, acc[p][rf][0], 0, 0, 0);
        acc[p][rf][1] = __builtin_amdgcn_mfma_f32_16x16x32_bf16(
            af, p == 0 ? wd1 : wa1, acc[p][rf][1], 0, 0, 0);
      }
    }
  }
  __builtin_amdgcn_s_setprio(0);

  // ---- epilogue ----
  const long nbase = (long)(b * NPTS + n) * NPTS + mbase;
  const int dbase = wid << 5;
#pragma unroll
  for (int cf = 0; cf < 2; ++cf) {
    const int dl = dbase + (cf << 4) + lrow;
    const float bias = bdv[dl] + bav[dl];
#pragma unroll
    for (int rf = 0; rf < 2; ++rf) {
      const f32x4 vd = acc[0][rf][cf];
      const f32x4 a0 = acc[1][rf][cf];
      const f32x4 a1 = acc[2][rf][cf];
      const f32x4 a2 = acc[3][rf][cf];
#pragma unroll
      for (int g = 0; g < 4; ++g) {
        const int mrow = (rf << 4) + ((lane >> 4) << 2) + g;
        const float val = vd[g] + fmaxf(fmaxf(a0[g], a1[g]), a2[g]) + bias;
        out[(nbase + mrow) * DDIM + dl] = val;
      }
    }
  }
}

// ---------------- fallback: validated R13 all-in-one kernel ----------------
__global__ __launch_bounds__(BLOCK, 1) void rpe_fused(
    const float* __restrict__ pts,
    const float* __restrict__ Wd, const float* __restrict__ bd,
    const float* __restrict__ Wa, const float* __restrict__ ba,
    float* __restrict__ out) {
#pragma clang fp contract(off)
  __shared__ alignas(16) unsigned char Elds[4 * MTILE * DDIM * 2];

  const int b = blockIdx.z;
  const int n = blockIdx.y;
  const int mbase = blockIdx.x * MTILE;
  const int tid = threadIdx.x;
  const int lane = tid & 63;

  const float* Pb = pts + b * NPTS * 3;
  const float pnx = Pb[n * 3 + 0], pny = Pb[n * 3 + 1], pnz = Pb[n * 3 + 2];
  const float sqn = (pnx * pnx + pny * pny) + pnz * pnz;

  unsigned long long key[4];
#pragma unroll
  for (int q = 0; q < 4; ++q) {
    const int m = lane + 64 * q;
    const float x = Pb[m * 3 + 0], y = Pb[m * 3 + 1], z = Pb[m * 3 + 2];
    const float sqm = (x * x + y * y) + z * z;
    const float dt = (pnx * x + pny * y) + pnz * z;
    const float d2 = (sqn + sqm) - 2.0f * dt;
    const float dist = sqrtf(fmaxf(d2, 0.0f));
    key[q] = ((unsigned long long)__builtin_bit_cast(unsigned int, dist) << 32) |
             (unsigned long long)(unsigned int)m;
  }
  int knn1 = 0, knn2 = 0, knn3 = 0;
#pragma unroll
  for (int r = 0; r < 4; ++r) {
    unsigned long long kmin = key[0];
#pragma unroll
    for (int q = 1; q < 4; ++q) kmin = (key[q] < kmin) ? key[q] : kmin;
#pragma unroll
    for (int off = 32; off > 0; off >>= 1) {
      unsigned long long o = shfl_xor_u64(kmin, off);
      kmin = (o < kmin) ? o : kmin;
    }
    const int widx = (int)(unsigned int)(kmin & 0xffffffffULL);
    if (r == 1) knn1 = widx;
    if (r == 2) knn2 = widx;
    if (r == 3) knn3 = widx;
#pragma unroll
    for (int q = 0; q < 4; ++q)
      if (key[q] == kmin) key[q] = ~0ULL;
  }
  const float r0x = Pb[knn1 * 3 + 0] - pnx, r0y = Pb[knn1 * 3 + 1] - pny, r0z = Pb[knn1 * 3 + 2] - pnz;
  const float r1x = Pb[knn2 * 3 + 0] - pnx, r1y = Pb[knn2 * 3 + 1] - pny, r1z = Pb[knn2 * 3 + 2] - pnz;
  const float r2x = Pb[knn3 * 3 + 0] - pnx, r2y = Pb[knn3 * 3 + 1] - pny, r2z = Pb[knn3 * 3 + 2] - pnz;

  {
    const int p = tid >> 7;
    const int r128 = tid & 127;
    const int ml = r128 & 31;
    const int k0 = (r128 >> 5) << 6;
    const int m = mbase + ml;
    const float pmx = Pb[m * 3 + 0], pmy = Pb[m * 3 + 1], pmz = Pb[m * 3 + 2];
    float xv;
    if (p == 0) {
      const float sqm = (pmx * pmx + pmy * pmy) + pmz * pmz;
      const float dt = (pnx * pmx + pny * pmy) + pnz * pmz;
      const float d2 = (sqn + sqm) - 2.0f * dt;
      xv = sqrtf(fmaxf(d2, 0.0f)) / 0.2f;
    } else {
      const float ax = pmx - pnx, ay = pmy - pny, az = pmz - pnz;
      const float rx = (p == 1) ? r0x : (p == 2) ? r1x : r2x;
      const float ry = (p == 1) ? r0y : (p == 2) ? r1y : r2y;
      const float rz = (p == 1) ? r0z : (p == 2) ? r1z : r2z;
      const float cx = ry * az - rz * ay;
      const float cy = rz * ax - rx * az;
      const float cz = rx * ay - ry * ax;
      const float sv = sqrtf((cx * cx + cy * cy) + cz * cz);
      const float cv = (rx * ax + ry * ay) + rz * az;
      float ang;
      if (sv == 0.0f && cv == 0.0f) ang = 0.0f;
      else ang = atan2f(sv, cv);
      xv = ang * 3.8197186342054885f;
    }
    const int row = (p << 5) + ml;
    const int swz = (ml & 7) << 4;
    const float c_exp = -0.10381025296523007f;
    const int jbase = k0 >> 1;
#pragma unroll
    for (int c = 0; c < 8; ++c) {
      s16x8 v;
#pragma unroll
      for (int jj = 0; jj < 4; ++jj) {
        const int j = jbase + c * 4 + jj;
        const float w = exp2f((float)j * c_exp);
        const float om = xv * w;
        float s, cc;
        __sincosf(om, &s, &cc);
        v[2 * jj] = f2bf(s);
        v[2 * jj + 1] = f2bf(cc);
      }
      const int boff = ((k0 << 1) + (c << 4)) ^ swz;
      *reinterpret_cast<s16x8*>(&Elds[row * 512 + boff]) = v;
    }
  }
  __syncthreads();

  const int wid = tid >> 6;
  const int dbase = wid << 5;
  const int lrow = lane & 15;
  const int lkb = (lane >> 4) << 3;

  f32x4 acc[4][2][2];
  const f32x4 zero = {0.0f, 0.0f, 0.0f, 0.0f};
#pragma unroll
  for (int p = 0; p < 4; ++p)
#pragma unroll
    for (int rf = 0; rf < 2; ++rf)
#pragma unroll
      for (int cf = 0; cf < 2; ++cf) acc[p][rf][cf] = zero;

#pragma unroll
  for (int ks = 0; ks < 8; ++ks) {
    const int kb = (ks << 5) + lkb;
    s16x8 bw[2][2];
#pragma unroll
    for (int cf = 0; cf < 2; ++cf) {
      const int dl = dbase + (cf << 4) + lrow;
      const float* wpd = Wd + dl * DDIM + kb;
      const float* wpa = Wa + dl * DDIM + kb;
      const f32x4 f0 = *reinterpret_cast<const f32x4*>(wpd);
      const f32x4 f1 = *reinterpret_cast<const f32x4*>(wpd + 4);
      const f32x4 g0 = *reinterpret_cast<const f32x4*>(wpa);
      const f32x4 g1 = *reinterpret_cast<const f32x4*>(wpa + 4);
      s16x8 vd, va;
#pragma unroll
      for (int e = 0; e < 4; ++e) {
        vd[e] = f2bf(f0[e]); vd[e + 4] = f2bf(f1[e]);
        va[e] = f2bf(g0[e]); va[e + 4] = f2bf(g1[e]);
      }
      bw[0][cf] = vd; bw[1][cf] = va;
    }
    const int kbyte = kb << 1;
#pragma unroll
    for (int rf = 0; rf < 2; ++rf) {
      const int mrow = (rf << 4) + lrow;
      const int boff = kbyte ^ ((mrow & 7) << 4);
#pragma unroll
      for (int p = 0; p < 4; ++p) {
        const s16x8 af =
            *reinterpret_cast<const s16x8*>(&Elds[((p << 5) + mrow) * 512 + boff]);
        acc[p][rf][0] = __builtin_amdgcn_mfma_f32_16x16x32_bf16(
            af, bw[p == 0 ? 0 : 1][0], acc[p][rf][0], 0, 0, 0);
        acc[p][rf][1] = __builtin_amdgcn_mfma_f32_16x16x32_bf16(
            af, bw[p == 0 ? 0 : 1][1], acc[p][rf][1], 0, 0, 0);
      }
    }
  }

  const long nbase = (long)(b * NPTS + n) * NPTS + mbase;
#pragma unroll
  for (int cf = 0; cf < 2; ++cf) {
    const int dl = dbase + (cf << 4) + lrow;
    const float bias = bd[dl] + ba[dl];
#pragma unroll
    for (int rf = 0; rf < 2; ++rf) {
      const f32x4 vd = acc[0][rf][cf];
      const f32x4 a0 = acc[1][rf][cf];
      const f32x4 a1 = acc[2][rf][cf];
      const f32x4 a2 = acc[3][rf][cf];
#pragma unroll
      for (int g = 0; g < 4; ++g) {
        const int mrow = (rf << 4) + ((lane >> 4) << 2) + g;
        const float val = vd[g] + fmaxf(fmaxf(a0[g], a1[g]), a2[g]) + bias;
        out[(nbase + mrow) * DDIM + dl] = val;
      }
    }
  }
}

extern "C" void kernel_launch(void* const* d_in, const int* in_sizes, int n_in,
                              void* d_out, int out_size, void* d_ws, size_t ws_size,
                              hipStream_t stream) {
  const float* pts = (const float*)d_in[0];
  const float* Wd  = (const float*)d_in[1];
  const float* bd  = (const float*)d_in[2];
  const float* Wa  = (const float*)d_in[3];
  const float* ba  = (const float*)d_in[4];
  float* out = (float*)d_out;
  const int B = in_sizes[0] / (NPTS * 3);
  const int total = B * NPTS;

  const size_t PW_BYTES = 16384 * 16;                 // 256 KB packed W
  const size_t need = PW_BYTES + (size_t)total * 3 * 4;
  dim3 grid(NPTS / MTILE, NPTS, B);

  if (ws_size >= need) {
    s16x8* PW = (s16x8*)d_ws;
    int* knn = (int*)((char*)d_ws + PW_BYTES);
    const int knn_blocks = (total + 3) / 4;
    prep<<<64 + knn_blocks, 256, 0, stream>>>(pts, Wd, Wa, PW, knn, total);
    rpe_main<<<grid, BLOCK, 0, stream>>>(pts, knn, PW, bd, ba, out);
  } else {
    rpe_fused<<<grid, BLOCK, 0, stream>>>(pts, Wd, bd, Wa, ba, out);
  }
}

// Round 23
// 82.248 us; speedup vs baseline: 1.2527x; 1.0018x over previous
//
#include <hip/hip_runtime.h>
#include <hip/hip_bf16.h>

#define NPTS 256
#define DDIM 256
#define MTILE 32
#define BLOCK 512

typedef __attribute__((ext_vector_type(4))) float f32x4;
typedef __attribute__((ext_vector_type(8))) short s16x8;

static __device__ __forceinline__ short f2bf(float f) {
  unsigned int u = __builtin_bit_cast(unsigned int, f);
  u += 0x7fffu + ((u >> 16) & 1u);   // round-to-nearest-even
  return (short)(unsigned short)(u >> 16);
}

static __device__ __forceinline__ unsigned long long shfl_xor_u64(unsigned long long v, int off) {
  unsigned int hi = (unsigned int)(v >> 32);
  unsigned int lo = (unsigned int)v;
  hi = (unsigned int)__shfl_xor((int)hi, off);
  lo = (unsigned int)__shfl_xor((int)lo, off);
  return ((unsigned long long)hi << 32) | (unsigned long long)lo;
}

// ---- fused prep: blocks 0..63 pack W; blocks 64.. wave-parallel kNN (R16-validated) ----
__global__ __launch_bounds__(256) void prep(const float* __restrict__ pts,
                                            const float* __restrict__ Wd,
                                            const float* __restrict__ Wa,
                                            s16x8* __restrict__ PW,
                                            int* __restrict__ knn_out, int total) {
#pragma clang fp contract(off)
  const int tid = threadIdx.x;
  if (blockIdx.x < 64) {
    const int flat = blockIdx.x * 256 + tid;     // 0..16383
    const int l = flat & 63;
    const int cf = (flat >> 6) & 1;
    const int ks = (flat >> 7) & 7;
    const int wid = (flat >> 10) & 7;
    const int mat = (flat >> 13) & 1;
    const float* W = mat ? Wa : Wd;
    const int dl = wid * 32 + cf * 16 + (l & 15);
    const int kb = ks * 32 + (l >> 4) * 8;
    const float* src = W + dl * DDIM + kb;
    const f32x4 f0 = *reinterpret_cast<const f32x4*>(src);
    const f32x4 f1 = *reinterpret_cast<const f32x4*>(src + 4);
    s16x8 v;
#pragma unroll
    for (int e = 0; e < 4; ++e) { v[e] = f2bf(f0[e]); v[e + 4] = f2bf(f1[e]); }
    PW[flat] = v;
    return;
  }
  const int task = (blockIdx.x - 64) * 4 + (tid >> 6);
  if (task >= total) return;
  const int lane = tid & 63;
  const int b = task >> 8, n = task & 255;
  const float* P = pts + b * 768;
  const float px = P[3 * n], py = P[3 * n + 1], pz = P[3 * n + 2];
  const float sqn = (px * px + py * py) + pz * pz;

  unsigned long long key[4];
#pragma unroll
  for (int q = 0; q < 4; ++q) {
    const int m = lane + 64 * q;
    const float x = P[3 * m], y = P[3 * m + 1], z = P[3 * m + 2];
    const float sqm = (x * x + y * y) + z * z;
    const float dt = (px * x + py * y) + pz * z;
    const float d2 = (sqn + sqm) - 2.0f * dt;
    const float dist = sqrtf(fmaxf(d2, 0.0f));
    key[q] = ((unsigned long long)__builtin_bit_cast(unsigned int, dist) << 32) |
             (unsigned long long)(unsigned int)m;
  }
  int kn[4];
#pragma unroll
  for (int r = 0; r < 4; ++r) {
    unsigned long long kmin = key[0];
#pragma unroll
    for (int q = 1; q < 4; ++q) kmin = (key[q] < kmin) ? key[q] : kmin;
#pragma unroll
    for (int off = 32; off > 0; off >>= 1) {
      unsigned long long o = shfl_xor_u64(kmin, off);
      kmin = (o < kmin) ? o : kmin;
    }
    kn[r] = (int)(unsigned int)(kmin & 0xffffffffULL);
#pragma unroll
    for (int q = 0; q < 4; ++q)
      if (key[q] == kmin) key[q] = ~0ULL;
  }
  if (lane == 0) {
    knn_out[task * 3 + 0] = kn[1];
    knn_out[task * 3 + 1] = kn[2];
    knn_out[task * 3 + 2] = kn[3];
  }
}

// ---- main kernel: R16 structure + bounds(512,4) + setprio — the R20 validated build ----
__global__ __launch_bounds__(BLOCK, 4) void rpe_main(
    const float* __restrict__ pts, const int* __restrict__ knn,
    const s16x8* __restrict__ PW,
    const float* __restrict__ bdv, const float* __restrict__ bav,
    float* __restrict__ out) {
#pragma clang fp contract(off)
  __shared__ alignas(16) unsigned char Elds[4 * MTILE * DDIM * 2];   // 64 KB

  const int b = blockIdx.z;
  const int n = blockIdx.y;
  const int mbase = blockIdx.x * MTILE;
  const int tid = threadIdx.x;
  const int lane = tid & 63;

  const float* Pb = pts + b * NPTS * 3;
  const float pnx = Pb[n * 3 + 0], pny = Pb[n * 3 + 1], pnz = Pb[n * 3 + 2];
  const float sqn = (pnx * pnx + pny * pny) + pnz * pnz;

  const int kb3 = (b * NPTS + n) * 3;
  const int kn1 = knn[kb3 + 0], kn2 = knn[kb3 + 1], kn3 = knn[kb3 + 2];
  const float r0x = Pb[kn1 * 3 + 0] - pnx, r0y = Pb[kn1 * 3 + 1] - pny, r0z = Pb[kn1 * 3 + 2] - pnz;
  const float r1x = Pb[kn2 * 3 + 0] - pnx, r1y = Pb[kn2 * 3 + 1] - pny, r1z = Pb[kn2 * 3 + 2] - pnz;
  const float r2x = Pb[kn3 * 3 + 0] - pnx, r2y = Pb[kn3 * 3 + 1] - pny, r2z = Pb[kn3 * 3 + 2] - pnz;

  // ---- E-tile generation (row-major, XOR-swizzled) ----
  {
    const int p = tid >> 7;           // 0..3
    const int r128 = tid & 127;
    const int ml = r128 & 31;
    const int k0 = (r128 >> 5) << 6;  // 0,64,128,192
    const int m = mbase + ml;
    const float pmx = Pb[m * 3 + 0], pmy = Pb[m * 3 + 1], pmz = Pb[m * 3 + 2];
    float xv;
    if (p == 0) {
      const float sqm = (pmx * pmx + pmy * pmy) + pmz * pmz;
      const float dt = (pnx * pmx + pny * pmy) + pnz * pmz;
      const float d2 = (sqn + sqm) - 2.0f * dt;
      xv = sqrtf(fmaxf(d2, 0.0f)) / 0.2f;
    } else {
      const float ax = pmx - pnx, ay = pmy - pny, az = pmz - pnz;
      const float rx = (p == 1) ? r0x : (p == 2) ? r1x : r2x;
      const float ry = (p == 1) ? r0y : (p == 2) ? r1y : r2y;
      const float rz = (p == 1) ? r0z : (p == 2) ? r1z : r2z;
      const float cx = ry * az - rz * ay;
      const float cy = rz * ax - rx * az;
      const float cz = rx * ay - ry * ax;
      const float sv = sqrtf((cx * cx + cy * cy) + cz * cz);
      const float cv = (rx * ax + ry * ay) + rz * az;
      // XLA +0 reduction-identity: a==0 -> cos=+0 -> angle 0 (never pi)
      float ang;
      if (sv == 0.0f && cv == 0.0f) ang = 0.0f;
      else ang = atan2f(sv, cv);
      xv = ang * 3.8197186342054885f;
    }
    const int row = (p << 5) + ml;
    const int swz = (ml & 7) << 4;
    const float c_exp = -0.10381025296523007f;     // -log2(10000)/128
    const int jbase = k0 >> 1;
    float w = exp2f((float)jbase * c_exp);
    const float step = 0.93057204f;                // 10000^(-1/128)
#pragma unroll
    for (int c = 0; c < 8; ++c) {
      int4 v;
#pragma unroll
      for (int jj = 0; jj < 4; ++jj) {
        const float om = xv * w;
        float s, cc;
        __sincosf(om, &s, &cc);
        unsigned int pk;
        asm("v_cvt_pk_bf16_f32 %0, %1, %2" : "=v"(pk) : "v"(s), "v"(cc));
        ((unsigned int*)&v)[jj] = pk;
        w *= step;
      }
      const int boff = ((k0 << 1) + (c << 4)) ^ swz;
      *reinterpret_cast<int4*>(&Elds[row * 512 + boff]) = v;
    }
  }
  __syncthreads();

  // ---- fused 4-path GEMM (setprio hints MFMA-phase waves over E-gen waves) ----
  const int wid = tid >> 6;
  const int lrow = lane & 15;

  f32x4 acc[4][2][2];
  const f32x4 zero = {0.0f, 0.0f, 0.0f, 0.0f};
#pragma unroll
  for (int p = 0; p < 4; ++p)
#pragma unroll
    for (int rf = 0; rf < 2; ++rf)
#pragma unroll
      for (int cf = 0; cf < 2; ++cf) acc[p][rf][cf] = zero;

  __builtin_amdgcn_s_setprio(1);
#pragma unroll
  for (int ks = 0; ks < 8; ++ks) {
    const int ib = ((wid * 8 + ks) * 2) * 64 + lane;
    const s16x8 wd0 = PW[ib];
    const s16x8 wd1 = PW[ib + 64];
    const s16x8 wa0 = PW[ib + 8192];
    const s16x8 wa1 = PW[ib + 8192 + 64];

    const int kb = (ks << 5) + ((lane >> 4) << 3);
    const int kbyte = kb << 1;
#pragma unroll
    for (int rf = 0; rf < 2; ++rf) {
      const int mrow = (rf << 4) + lrow;
      const int boff = kbyte ^ ((mrow & 7) << 4);
#pragma unroll
      for (int p = 0; p < 4; ++p) {
        const s16x8 af =
            *reinterpret_cast<const s16x8*>(&Elds[((p << 5) + mrow) * 512 + boff]);
        acc[p][rf][0] = __builtin_amdgcn_mfma_f32_16x16x32_bf16(
            af, p == 0 ? wd0 : wa0, acc[p][rf][0], 0, 0, 0);
        acc[p][rf][1] = __builtin_amdgcn_mfma_f32_16x16x32_bf16(
            af, p == 0 ? wd1 : wa1, acc[p][rf][1], 0, 0, 0);
      }
    }
  }
  __builtin_amdgcn_s_setprio(0);

  // ---- epilogue ----
  const long nbase = (long)(b * NPTS + n) * NPTS + mbase;
  const int dbase = wid << 5;
#pragma unroll
  for (int cf = 0; cf < 2; ++cf) {
    const int dl = dbase + (cf << 4) + lrow;
    const float bias = bdv[dl] + bav[dl];
#pragma unroll
    for (int rf = 0; rf < 2; ++rf) {
      const f32x4 vd = acc[0][rf][cf];
      const f32x4 a0 = acc[1][rf][cf];
      const f32x4 a1 = acc[2][rf][cf];
      const f32x4 a2 = acc[3][rf][cf];
#pragma unroll
      for (int g = 0; g < 4; ++g) {
        const int mrow = (rf << 4) + ((lane >> 4) << 2) + g;
        const float val = vd[g] + fmaxf(fmaxf(a0[g], a1[g]), a2[g]) + bias;
        out[(nbase + mrow) * DDIM + dl] = val;
      }
    }
  }
}

// ---------------- fallback: validated R13 all-in-one kernel ----------------
__global__ __launch_bounds__(BLOCK, 1) void rpe_fused(
    const float* __restrict__ pts,
    const float* __restrict__ Wd, const float* __restrict__ bd,
    const float* __restrict__ Wa, const float* __restrict__ ba,
    float* __restrict__ out) {
#pragma clang fp contract(off)
  __shared__ alignas(16) unsigned char Elds[4 * MTILE * DDIM * 2];

  const int b = blockIdx.z;
  const int n = blockIdx.y;
  const int mbase = blockIdx.x * MTILE;
  const int tid = threadIdx.x;
  const int lane = tid & 63;

  const float* Pb = pts + b * NPTS * 3;
  const float pnx = Pb[n * 3 + 0], pny = Pb[n * 3 + 1], pnz = Pb[n * 3 + 2];
  const float sqn = (pnx * pnx + pny * pny) + pnz * pnz;

  unsigned long long key[4];
#pragma unroll
  for (int q = 0; q < 4; ++q) {
    const int m = lane + 64 * q;
    const float x = Pb[m * 3 + 0], y = Pb[m * 3 + 1], z = Pb[m * 3 + 2];
    const float sqm = (x * x + y * y) + z * z;
    const float dt = (pnx * x + pny * y) + pnz * z;
    const float d2 = (sqn + sqm) - 2.0f * dt;
    const float dist = sqrtf(fmaxf(d2, 0.0f));
    key[q] = ((unsigned long long)__builtin_bit_cast(unsigned int, dist) << 32) |
             (unsigned long long)(unsigned int)m;
  }
  int knn1 = 0, knn2 = 0, knn3 = 0;
#pragma unroll
  for (int r = 0; r < 4; ++r) {
    unsigned long long kmin = key[0];
#pragma unroll
    for (int q = 1; q < 4; ++q) kmin = (key[q] < kmin) ? key[q] : kmin;
#pragma unroll
    for (int off = 32; off > 0; off >>= 1) {
      unsigned long long o = shfl_xor_u64(kmin, off);
      kmin = (o < kmin) ? o : kmin;
    }
    const int widx = (int)(unsigned int)(kmin & 0xffffffffULL);
    if (r == 1) knn1 = widx;
    if (r == 2) knn2 = widx;
    if (r == 3) knn3 = widx;
#pragma unroll
    for (int q = 0; q < 4; ++q)
      if (key[q] == kmin) key[q] = ~0ULL;
  }
  const float r0x = Pb[knn1 * 3 + 0] - pnx, r0y = Pb[knn1 * 3 + 1] - pny, r0z = Pb[knn1 * 3 + 2] - pnz;
  const float r1x = Pb[knn2 * 3 + 0] - pnx, r1y = Pb[knn2 * 3 + 1] - pny, r1z = Pb[knn2 * 3 + 2] - pnz;
  const float r2x = Pb[knn3 * 3 + 0] - pnx, r2y = Pb[knn3 * 3 + 1] - pny, r2z = Pb[knn3 * 3 + 2] - pnz;

  {
    const int p = tid >> 7;
    const int r128 = tid & 127;
    const int ml = r128 & 31;
    const int k0 = (r128 >> 5) << 6;
    const int m = mbase + ml;
    const float pmx = Pb[m * 3 + 0], pmy = Pb[m * 3 + 1], pmz = Pb[m * 3 + 2];
    float xv;
    if (p == 0) {
      const float sqm = (pmx * pmx + pmy * pmy) + pmz * pmz;
      const float dt = (pnx * pmx + pny * pmy) + pnz * pmz;
      const float d2 = (sqn + sqm) - 2.0f * dt;
      xv = sqrtf(fmaxf(d2, 0.0f)) / 0.2f;
    } else {
      const float ax = pmx - pnx, ay = pmy - pny, az = pmz - pnz;
      const float rx = (p == 1) ? r0x : (p == 2) ? r1x : r2x;
      const float ry = (p == 1) ? r0y : (p == 2) ? r1y : r2y;
      const float rz = (p == 1) ? r0z : (p == 2) ? r1z : r2z;
      const float cx = ry * az - rz * ay;
      const float cy = rz * ax - rx * az;
      const float cz = rx * ay - ry * ax;
      const float sv = sqrtf((cx * cx + cy * cy) + cz * cz);
      const float cv = (rx * ax + ry * ay) + rz * az;
      float ang;
      if (sv == 0.0f && cv == 0.0f) ang = 0.0f;
      else ang = atan2f(sv, cv);
      xv = ang * 3.8197186342054885f;
    }
    const int row = (p << 5) + ml;
    const int swz = (ml & 7) << 4;
    const float c_exp = -0.10381025296523007f;
    const int jbase = k0 >> 1;
#pragma unroll
    for (int c = 0; c < 8; ++c) {
      s16x8 v;
#pragma unroll
      for (int jj = 0; jj < 4; ++jj) {
        const int j = jbase + c * 4 + jj;
        const float w = exp2f((float)j * c_exp);
        const float om = xv * w;
        float s, cc;
        __sincosf(om, &s, &cc);
        v[2 * jj] = f2bf(s);
        v[2 * jj + 1] = f2bf(cc);
      }
      const int boff = ((k0 << 1) + (c << 4)) ^ swz;
      *reinterpret_cast<s16x8*>(&Elds[row * 512 + boff]) = v;
    }
  }
  __syncthreads();

  const int wid = tid >> 6;
  const int dbase = wid << 5;
  const int lrow = lane & 15;
  const int lkb = (lane >> 4) << 3;

  f32x4 acc[4][2][2];
  const f32x4 zero = {0.0f, 0.0f, 0.0f, 0.0f};
#pragma unroll
  for (int p = 0; p < 4; ++p)
#pragma unroll
    for (int rf = 0; rf < 2; ++rf)
#pragma unroll
      for (int cf = 0; cf < 2; ++cf) acc[p][rf][cf] = zero;

#pragma unroll
  for (int ks = 0; ks < 8; ++ks) {
    const int kb = (ks << 5) + lkb;
    s16x8 bw[2][2];
#pragma unroll
    for (int cf = 0; cf < 2; ++cf) {
      const int dl = dbase + (cf << 4) + lrow;
      const float* wpd = Wd + dl * DDIM + kb;
      const float* wpa = Wa + dl * DDIM + kb;
      const f32x4 f0 = *reinterpret_cast<const f32x4*>(wpd);
      const f32x4 f1 = *reinterpret_cast<const f32x4*>(wpd + 4);
      const f32x4 g0 = *reinterpret_cast<const f32x4*>(wpa);
      const f32x4 g1 = *reinterpret_cast<const f32x4*>(wpa + 4);
      s16x8 vd, va;
#pragma unroll
      for (int e = 0; e < 4; ++e) {
        vd[e] = f2bf(f0[e]); vd[e + 4] = f2bf(f1[e]);
        va[e] = f2bf(g0[e]); va[e + 4] = f2bf(g1[e]);
      }
      bw[0][cf] = vd; bw[1][cf] = va;
    }
    const int kbyte = kb << 1;
#pragma unroll
    for (int rf = 0; rf < 2; ++rf) {
      const int mrow = (rf << 4) + lrow;
      const int boff = kbyte ^ ((mrow & 7) << 4);
#pragma unroll
      for (int p = 0; p < 4; ++p) {
        const s16x8 af =
            *reinterpret_cast<const s16x8*>(&Elds[((p << 5) + mrow) * 512 + boff]);
        acc[p][rf][0] = __builtin_amdgcn_mfma_f32_16x16x32_bf16(
            af, bw[p == 0 ? 0 : 1][0], acc[p][rf][0], 0, 0, 0);
        acc[p][rf][1] = __builtin_amdgcn_mfma_f32_16x16x32_bf16(
            af, bw[p == 0 ? 0 : 1][1], acc[p][rf][1], 0, 0, 0);
      }
    }
  }

  const long nbase = (long)(b * NPTS + n) * NPTS + mbase;
#pragma unroll
  for (int cf = 0; cf < 2; ++cf) {
    const int dl = dbase + (cf << 4) + lrow;
    const float bias = bd[dl] + ba[dl];
#pragma unroll
    for (int rf = 0; rf < 2; ++rf) {
      const f32x4 vd = acc[0][rf][cf];
      const f32x4 a0 = acc[1][rf][cf];
      const f32x4 a1 = acc[2][rf][cf];
      const f32x4 a2 = acc[3][rf][cf];
#pragma unroll
      for (int g = 0; g < 4; ++g) {
        const int mrow = (rf << 4) + ((lane >> 4) << 2) + g;
        const float val = vd[g] + fmaxf(fmaxf(a0[g], a1[g]), a2[g]) + bias;
        out[(nbase + mrow) * DDIM + dl] = val;
      }
    }
  }
}

extern "C" void kernel_launch(void* const* d_in, const int* in_sizes, int n_in,
                              void* d_out, int out_size, void* d_ws, size_t ws_size,
                              hipStream_t stream) {
  const float* pts = (const float*)d_in[0];
  const float* Wd  = (const float*)d_in[1];
  const float* bd  = (const float*)d_in[2];
  const float* Wa  = (const float*)d_in[3];
  const float* ba  = (const float*)d_in[4];
  float* out = (float*)d_out;
  const int B = in_sizes[0] / (NPTS * 3);
  const int total = B * NPTS;

  const size_t PW_BYTES = 16384 * 16;                 // 256 KB packed W
  const size_t need = PW_BYTES + (size_t)total * 3 * 4;
  dim3 grid(NPTS / MTILE, NPTS, B);

  if (ws_size >= need) {
    s16x8* PW = (s16x8*)d_ws;
    int* knn = (int*)((char*)d_ws + PW_BYTES);
    const int knn_blocks = (total + 3) / 4;
    prep<<<64 + knn_blocks, 256, 0, stream>>>(pts, Wd, Wa, PW, knn, total);
    rpe_main<<<grid, BLOCK, 0, stream>>>(pts, knn, PW, bd, ba, out);
  } else {
    rpe_fused<<<grid, BLOCK, 0, stream>>>(pts, Wd, bd, Wa, ba, out);
  }
}